// Round 7
// baseline (4782.463 us; speedup 1.0000x reference)
//
#include <hip/hip_runtime.h>
#include <hip/hip_bf16.h>

// LoRA forward on MI355X:
//   out = x @ W^T + 2.0 * (x @ A^T) @ B^T
// W_eff = W + 2*(B@A) in bf16, xb = bf16(x); one bf16 MFMA GEMM
// C[16384,4096] = xb @ W_eff^T, 256x256 8-phase schedule, 16x16x32 MFMA.
// Round-7: SINGLE-buffer 4-slot LDS ring (64 KiB) -> 2 blocks/CU,
// 4 waves/SIMD; provable WAR/RAW ledger (drain-then-barrier before every
// restage); counted vmcnt 2->6->4->2 (never 0); chunk-XOR swizzle.

typedef __bf16 bf16;
typedef bf16 bf16x8 __attribute__((ext_vector_type(8)));
typedef float f32x4 __attribute__((ext_vector_type(4)));

typedef __attribute__((address_space(1))) const void* as1cv;
typedef __attribute__((address_space(3))) void* as3v;

constexpr int Mdim = 16384;
constexpr int Ndim = 4096;
constexpr int Kdim = 4096;
constexpr int Rdim = 8;
constexpr float kScale = 2.0f;  // lora_alpha / r = 16/8

__device__ __forceinline__ unsigned short f2bf(float f) {
  union { float f; unsigned u; } v; v.f = f;
  unsigned u = v.u;
  u += 0x7fffu + ((u >> 16) & 1u);   // round-to-nearest-even
  return (unsigned short)(u >> 16);
}

// ---------------- Kernel 1: cast x (f32) -> xb (bf16) ----------------
__global__ void cast_x_kernel(const float4* __restrict__ x4,
                              ushort4* __restrict__ o4, int n4) {
  int i = blockIdx.x * blockDim.x + threadIdx.x;
  int stride = gridDim.x * blockDim.x;
  for (; i < n4; i += stride) {
    float4 v = x4[i];
    ushort4 o;
    o.x = f2bf(v.x); o.y = f2bf(v.y); o.z = f2bf(v.z); o.w = f2bf(v.w);
    o4[i] = o;
  }
}

// ---------------- Kernel 2: W_eff = W + 2*(B@A), cast to bf16 --------
__global__ void make_weff_kernel(const float* __restrict__ W,
                                 const float* __restrict__ A,
                                 const float* __restrict__ Bm,
                                 ushort* __restrict__ weff) {
  int tid = blockIdx.x * blockDim.x + threadIdx.x;
  int kc = tid & 511;       // K/8 = 512
  int n = tid >> 9;
  if (n >= Ndim) return;

  const float* wp = W + (long)n * Kdim + kc * 8;
  float4 w0 = *(const float4*)(wp);
  float4 w1 = *(const float4*)(wp + 4);

  float4 b0 = *(const float4*)(Bm + n * Rdim);
  float4 b1 = *(const float4*)(Bm + n * Rdim + 4);
  float bs[8] = {b0.x, b0.y, b0.z, b0.w, b1.x, b1.y, b1.z, b1.w};

  float l[8] = {0.f, 0.f, 0.f, 0.f, 0.f, 0.f, 0.f, 0.f};
#pragma unroll
  for (int r = 0; r < Rdim; ++r) {
    const float* ap = A + (long)r * Kdim + kc * 8;
    float4 a0 = *(const float4*)(ap);
    float4 a1 = *(const float4*)(ap + 4);
    l[0] += bs[r] * a0.x; l[1] += bs[r] * a0.y;
    l[2] += bs[r] * a0.z; l[3] += bs[r] * a0.w;
    l[4] += bs[r] * a1.x; l[5] += bs[r] * a1.y;
    l[6] += bs[r] * a1.z; l[7] += bs[r] * a1.w;
  }

  float o[8] = {w0.x + kScale * l[0], w0.y + kScale * l[1],
                w0.z + kScale * l[2], w0.w + kScale * l[3],
                w1.x + kScale * l[4], w1.y + kScale * l[5],
                w1.z + kScale * l[6], w1.w + kScale * l[7]};
  uint4 pk;
  pk.x = (unsigned)f2bf(o[0]) | ((unsigned)f2bf(o[1]) << 16);
  pk.y = (unsigned)f2bf(o[2]) | ((unsigned)f2bf(o[3]) << 16);
  pk.z = (unsigned)f2bf(o[4]) | ((unsigned)f2bf(o[5]) << 16);
  pk.w = (unsigned)f2bf(o[6]) | ((unsigned)f2bf(o[7]) << 16);
  *(uint4*)(weff + (long)n * Kdim + kc * 8) = pk;
}

// ---------------- Kernel 3: C = xb @ W_eff^T, 256^2 single-buf ring --
#define BM 256
#define BN 256
#define BK 64
#define NT (Kdim / BK)   // 64 K-tiles

#define SCHED0 __builtin_amdgcn_sched_barrier(0)
#define BAR __builtin_amdgcn_s_barrier()
#define VMCNT(n) asm volatile("s_waitcnt vmcnt(" #n ")" ::: "memory")
// LGKM keeps a trailing SCHED0: rule #18 (MFMA hoists past inline-asm waits)
#define LGKM(n) do { asm volatile("s_waitcnt lgkmcnt(" #n ")" ::: "memory"); SCHED0; } while (0)
#define GLOAD(src, dst) \
  __builtin_amdgcn_global_load_lds((as1cv)(src), (as3v)(dst), 16, 0, 0)

// Halves by CONSUMPTION quadrant (phase):
//   A half mh: rows { wr*128 + mh*64 + [0,64) : wr=0,1 }
//   B half nh: rows { wc*64 + nh*32 + [0,32) : wc=0..3 }
// Chunk-XOR swizzle: stored 16B chunk cs of row s holds logical chunk cs^(s&7).

__global__ __launch_bounds__(512, 4) void gemm256(const bf16* __restrict__ Xb,
                                                  const bf16* __restrict__ Wb,
                                                  float* __restrict__ C) {
  __shared__ bf16 lds[2][2][128 * 64];  // [A/B][half][8192] = 64 KiB

  const int tid = threadIdx.x;
  const int lane = tid & 63;
  const int wave = tid >> 6;
  const int wr = wave >> 2;    // 0..1  (M half)
  const int wc = wave & 3;     // 0..3  (N quarter)
  const int fr = lane & 15;
  const int fq = lane >> 4;

  // XCD-aware bijective swizzle: 1024 blocks, 8 XCDs, 128 contiguous per XCD
  const int wg = blockIdx.x;
  const int swz = (wg & 7) * 128 + (wg >> 3);
  const int by = swz >> 4;     // 0..63  (M block)
  const int bx = swz & 15;     // 0..15  (N block)
  const int brow = by * BM;
  const int bcol = bx * BN;

  // ---- staging pointers (per thread): storage row sLow, swizzled chunk
  const int sLow = tid >> 3;                       // 0..63
  const int cg = (tid & 7) ^ (sLow & 7);           // logical chunk (involution)
  const bf16* pA = Xb + (long)(brow + sLow) * Kdim + cg * 8;
  const bf16* pB =
      Wb + (long)(bcol + (sLow & 31) + (sLow >> 5) * 64) * Kdim + cg * 8;

#define STAGE_A(h, kt) do {                                                   \
    const bf16* s_ = pA + (long)((h) * 64) * Kdim + (((kt) & (NT - 1)) * 64); \
    GLOAD(s_, &lds[0][h][0] + tid * 8);                                       \
    GLOAD(s_ + (long)128 * Kdim, &lds[0][h][4096] + tid * 8);                 \
  } while (0)
#define STAGE_B(h, kt) do {                                                   \
    const bf16* s_ = pB + (long)((h) * 32) * Kdim + (((kt) & (NT - 1)) * 64); \
    GLOAD(s_, &lds[1][h][0] + tid * 8);                                       \
    GLOAD(s_ + (long)128 * Kdim, &lds[1][h][4096] + tid * 8);                 \
  } while (0)

  // ---- frag-read bases (swizzled)
  const bf16* aB0 = &lds[0][0][(wr * 64 + fr) * 64];
  const bf16* bB0 = &lds[1][0][(wc * 32 + fr) * 64];
  const int cofs0 = ((fq + 0) ^ (fr & 7)) * 8;   // kk=0 chunk
  const int cofs1 = ((fq + 4) ^ (fr & 7)) * 8;   // kk=1 chunk

  f32x4 acc[8][4];
#pragma unroll
  for (int m = 0; m < 8; ++m)
#pragma unroll
    for (int n = 0; n < 4; ++n)
      acc[m][n] = (f32x4){0.f, 0.f, 0.f, 0.f};

  bf16x8 aF0[4][2];    // A-half-0 frags (read cross-tile at P3)
  bf16x8 aF1[4][2];    // A-half-1 frags (read at P1)
  bf16x8 bF[2][2][2];  // [nh][n2][kk]; bF0 read cross-tile at P3

#define LDA(dst, mh)                                                          \
  { _Pragma("unroll") for (int m4 = 0; m4 < 4; ++m4) {                        \
      dst[m4][0] = *(const bf16x8*)(aB0 + (mh) * 8192 + m4 * 1024 + cofs0);   \
      dst[m4][1] = *(const bf16x8*)(aB0 + (mh) * 8192 + m4 * 1024 + cofs1);   \
  } }
#define LDB(nh)                                                               \
  { _Pragma("unroll") for (int n2 = 0; n2 < 2; ++n2) {                        \
      bF[nh][n2][0] = *(const bf16x8*)(bB0 + (nh) * 8192 + n2 * 1024 + cofs0);\
      bF[nh][n2][1] = *(const bf16x8*)(bB0 + (nh) * 8192 + n2 * 1024 + cofs1);\
  } }
#define MFMAQ(areg, mh, nh)                                                   \
  { __builtin_amdgcn_s_setprio(1);                                            \
    _Pragma("unroll") for (int m4 = 0; m4 < 4; ++m4)                          \
    _Pragma("unroll") for (int n2 = 0; n2 < 2; ++n2)                          \
    _Pragma("unroll") for (int kk = 0; kk < 2; ++kk)                          \
      acc[(mh) * 4 + m4][(nh) * 2 + n2] =                                     \
          __builtin_amdgcn_mfma_f32_16x16x32_bf16(                            \
              areg[m4][kk], bF[nh][n2][kk], acc[(mh) * 4 + m4][(nh) * 2 + n2],\
              0, 0, 0);                                                       \
    __builtin_amdgcn_s_setprio(0); }

  // Single-buffer ring, quadrants (0,0)@P0 (0,1)@P1 (1,1)@P2 (1,0)@P3.
  // WAR (restage >= drain + barrier later):
  //   A0,B0@P0 <- P3's LGKM(0)+BAR;  B1@P2 <- P1's LGKM(8)+BAR (in-order
  //   DS retire drains B1's 4 first); A1@P3 <- P2's LGKM(0)+BAR.
  // RAW (read >= VMCNT certify + barrier later):
  //   A1 read@P1 <- VMCNT(4)@P0; A0,B0 read@P3 <- VMCNT(2)@P2;
  //   B1 read@P0(t+1) <- VMCNT(2)@P3.  In-flight: 2 -> 6 -> 4 -> 2.
#define TILE(t) do {                                                          \
    /* P0 */                                                                  \
    STAGE_A(0, (t) + 1);                                                      \
    STAGE_B(0, (t) + 1);                                                      \
    LDB(1);                                                                   \
    VMCNT(4);                                                                 \
    BAR;                                                                      \
    MFMAQ(aF0, 0, 0); BAR;                                                    \
    /* P1 */                                                                  \
    LDA(aF1, 1);                                                              \
    BAR; LGKM(8);                                                             \
    MFMAQ(aF0, 0, 1); BAR;                                                    \
    /* P2 */                                                                  \
    STAGE_B(1, (t) + 1);                                                      \
    BAR; LGKM(0);                                                             \
    MFMAQ(aF1, 1, 1);                                                         \
    VMCNT(2); BAR;                                                            \
    /* P3 */                                                                  \
    MFMAQ(aF1, 1, 0);                                                         \
    STAGE_A(1, (t) + 1);                                                      \
    LDA(aF0, 0);                                                              \
    LDB(0);                                                                   \
    LGKM(0);                                                                  \
    VMCNT(2); BAR;                                                            \
  } while (0)

  // ---- prologue: stage tile0's 4 slots, preload aF0/bF0, enter steady state
  STAGE_A(0, 0);
  STAGE_B(0, 0);
  STAGE_B(1, 0);
  STAGE_A(1, 0);
  VMCNT(4); BAR;        // A0,B0 landed (in-order; leaves B1,A1's 4)
  LDA(aF0, 0);
  LDB(0);
  LGKM(0);              // drain (P0 of tile0 overwrites A0,B0)
  VMCNT(2); BAR;        // B1 landed (leaves A1's 2) -> matches steady state

#pragma unroll 1
  for (int t = 0; t < NT; ++t) TILE(t);  // tail wrap-dummies: last tile's
  VMCNT(0);                              // cross-tile preload regs unused
  LGKM(0);

  // ---- epilogue: C/D layout col=lane&15, row=(lane>>4)*4+reg
  const int crow = brow + wr * 128 + fq * 4;
  const int ccol = bcol + wc * 64 + fr;
#pragma unroll
  for (int m = 0; m < 8; ++m) {
#pragma unroll
    for (int n = 0; n < 4; ++n) {
      f32x4 v = acc[m][n];
      long base = (long)(crow + m * 16) * Ndim + (ccol + n * 16);
      C[base] = v[0];
      C[base + Ndim] = v[1];
      C[base + 2 * (long)Ndim] = v[2];
      C[base + 3 * (long)Ndim] = v[3];
    }
  }
}

extern "C" void kernel_launch(void* const* d_in, const int* in_sizes, int n_in,
                              void* d_out, int out_size, void* d_ws,
                              size_t ws_size, hipStream_t stream) {
  const float* x = (const float*)d_in[0];       // [4,4096,4096] -> [M,K]
  const float* W = (const float*)d_in[1];       // [N,K]
  const float* lA = (const float*)d_in[2];      // [R,K]
  const float* lB = (const float*)d_in[3];      // [N,R]
  float* out = (float*)d_out;                   // [M,N] f32

  ushort* xb = (ushort*)d_ws;                          // M*K bf16 = 134 MB
  ushort* weff = xb + (size_t)Mdim * Kdim;             // N*K bf16 = 33.5 MB

  cast_x_kernel<<<2048, 256, 0, stream>>>((const float4*)x, (ushort4*)xb,
                                          (Mdim * Kdim) / 4);
  make_weff_kernel<<<(Ndim * (Kdim / 8)) / 256, 256, 0, stream>>>(W, lA, lB,
                                                                  weff);
  dim3 grid((Mdim / BM) * (Ndim / BN));  // 64*16 = 1024 blocks
  gemm256<<<grid, 512, 0, stream>>>((const bf16*)xb, (const bf16*)weff, out);
}

// Round 8
// 570.063 us; speedup vs baseline: 8.3894x; 8.3894x over previous
//
#include <hip/hip_runtime.h>
#include <hip/hip_bf16.h>

// LoRA forward on MI355X:
//   out = x @ W^T + 2.0 * (x @ A^T) @ B^T
// W_eff = W + 2*(B@A) in bf16, xb = bf16(x); one bf16 MFMA GEMM
// C[16384,4096] = xb @ W_eff^T, 256x256 8-phase, 16x16x32 MFMA, dbuf LDS.
// Round-8: quadrant order (0,0)(0,1)(1,0)(1,1) so aF0/bF0 are dead by end
// of P2 -> the 12 cross-tile preload reads move to end-of-P2 (post-vmcnt)
// and overlap MFMA(1,1)@P3. Every ds_read now overlaps an MFMA cluster.
// (r7's 2-blocks/CU attempt reverted: 256-reg/wave footprint forces spills.)

typedef __bf16 bf16;
typedef bf16 bf16x8 __attribute__((ext_vector_type(8)));
typedef float f32x4 __attribute__((ext_vector_type(4)));

typedef __attribute__((address_space(1))) const void* as1cv;
typedef __attribute__((address_space(3))) void* as3v;

constexpr int Mdim = 16384;
constexpr int Ndim = 4096;
constexpr int Kdim = 4096;
constexpr int Rdim = 8;
constexpr float kScale = 2.0f;  // lora_alpha / r = 16/8

__device__ __forceinline__ unsigned short f2bf(float f) {
  union { float f; unsigned u; } v; v.f = f;
  unsigned u = v.u;
  u += 0x7fffu + ((u >> 16) & 1u);   // round-to-nearest-even
  return (unsigned short)(u >> 16);
}

// ---------------- Kernel 1: cast x (f32) -> xb (bf16) ----------------
__global__ void cast_x_kernel(const float4* __restrict__ x4,
                              ushort4* __restrict__ o4, int n4) {
  int i = blockIdx.x * blockDim.x + threadIdx.x;
  int stride = gridDim.x * blockDim.x;
  for (; i < n4; i += stride) {
    float4 v = x4[i];
    ushort4 o;
    o.x = f2bf(v.x); o.y = f2bf(v.y); o.z = f2bf(v.z); o.w = f2bf(v.w);
    o4[i] = o;
  }
}

// ---------------- Kernel 2: W_eff = W + 2*(B@A), cast to bf16 --------
__global__ void make_weff_kernel(const float* __restrict__ W,
                                 const float* __restrict__ A,
                                 const float* __restrict__ Bm,
                                 ushort* __restrict__ weff) {
  int tid = blockIdx.x * blockDim.x + threadIdx.x;
  int kc = tid & 511;       // K/8 = 512
  int n = tid >> 9;
  if (n >= Ndim) return;

  const float* wp = W + (long)n * Kdim + kc * 8;
  float4 w0 = *(const float4*)(wp);
  float4 w1 = *(const float4*)(wp + 4);

  float4 b0 = *(const float4*)(Bm + n * Rdim);
  float4 b1 = *(const float4*)(Bm + n * Rdim + 4);
  float bs[8] = {b0.x, b0.y, b0.z, b0.w, b1.x, b1.y, b1.z, b1.w};

  float l[8] = {0.f, 0.f, 0.f, 0.f, 0.f, 0.f, 0.f, 0.f};
#pragma unroll
  for (int r = 0; r < Rdim; ++r) {
    const float* ap = A + (long)r * Kdim + kc * 8;
    float4 a0 = *(const float4*)(ap);
    float4 a1 = *(const float4*)(ap + 4);
    l[0] += bs[r] * a0.x; l[1] += bs[r] * a0.y;
    l[2] += bs[r] * a0.z; l[3] += bs[r] * a0.w;
    l[4] += bs[r] * a1.x; l[5] += bs[r] * a1.y;
    l[6] += bs[r] * a1.z; l[7] += bs[r] * a1.w;
  }

  float o[8] = {w0.x + kScale * l[0], w0.y + kScale * l[1],
                w0.z + kScale * l[2], w0.w + kScale * l[3],
                w1.x + kScale * l[4], w1.y + kScale * l[5],
                w1.z + kScale * l[6], w1.w + kScale * l[7]};
  uint4 pk;
  pk.x = (unsigned)f2bf(o[0]) | ((unsigned)f2bf(o[1]) << 16);
  pk.y = (unsigned)f2bf(o[2]) | ((unsigned)f2bf(o[3]) << 16);
  pk.z = (unsigned)f2bf(o[4]) | ((unsigned)f2bf(o[5]) << 16);
  pk.w = (unsigned)f2bf(o[6]) | ((unsigned)f2bf(o[7]) << 16);
  *(uint4*)(weff + (long)n * Kdim + kc * 8) = pk;
}

// ---------------- Kernel 3: C = xb @ W_eff^T, 256^2 8-phase ----------
#define BM 256
#define BN 256
#define BK 64
#define NT (Kdim / BK)   // 64 K-tiles

#define SCHED0 __builtin_amdgcn_sched_barrier(0)
#define BAR __builtin_amdgcn_s_barrier()
#define VMCNT(n) asm volatile("s_waitcnt vmcnt(" #n ")" ::: "memory")
// LGKM keeps a trailing SCHED0: rule #18 (MFMA hoists past inline-asm waits)
#define LGKM(n) do { asm volatile("s_waitcnt lgkmcnt(" #n ")" ::: "memory"); SCHED0; } while (0)
#define GLOAD(src, dst) \
  __builtin_amdgcn_global_load_lds((as1cv)(src), (as3v)(dst), 16, 0, 0)

// Halves by CONSUMPTION quadrant (phase):
//   A half mh: rows { wr*128 + mh*64 + [0,64) : wr=0,1 }
//   B half nh: rows { wc*64 + nh*32 + [0,32) : wc=0..3 }
// Chunk-XOR swizzle: stored 16B chunk cs of row s holds logical chunk cs^(s&7).

__global__ __launch_bounds__(512, 2) void gemm256(const bf16* __restrict__ Xb,
                                                  const bf16* __restrict__ Wb,
                                                  float* __restrict__ C) {
  __shared__ bf16 lds[2][2][2][128 * 64];  // [dbuf][A/B][half][8192] = 128 KiB

  const int tid = threadIdx.x;
  const int lane = tid & 63;
  const int wave = tid >> 6;
  const int wr = wave >> 2;    // 0..1  (M half)
  const int wc = wave & 3;     // 0..3  (N quarter)
  const int fr = lane & 15;
  const int fq = lane >> 4;

  // XCD-aware bijective swizzle: 1024 blocks, 8 XCDs, 128 contiguous per XCD
  const int wg = blockIdx.x;
  const int swz = (wg & 7) * 128 + (wg >> 3);
  const int by = swz >> 4;     // 0..63  (M block)
  const int bx = swz & 15;     // 0..15  (N block)
  const int brow = by * BM;
  const int bcol = bx * BN;

  // ---- staging pointers (per thread): storage row sLow, swizzled chunk
  const int sLow = tid >> 3;                       // 0..63
  const int cg = (tid & 7) ^ (sLow & 7);           // logical chunk (involution)
  const bf16* pA = Xb + (long)(brow + sLow) * Kdim + cg * 8;
  const bf16* pB =
      Wb + (long)(bcol + (sLow & 31) + (sLow >> 5) * 64) * Kdim + cg * 8;

#define STAGE_A(buf, h, kt) do {                                              \
    const bf16* s_ = pA + (long)((h) * 64) * Kdim + (((kt) & (NT - 1)) * 64); \
    GLOAD(s_, &lds[buf][0][h][0] + tid * 8);                                  \
    GLOAD(s_ + (long)128 * Kdim, &lds[buf][0][h][4096] + tid * 8);            \
  } while (0)
#define STAGE_B(buf, h, kt) do {                                              \
    const bf16* s_ = pB + (long)((h) * 32) * Kdim + (((kt) & (NT - 1)) * 64); \
    GLOAD(s_, &lds[buf][1][h][0] + tid * 8);                                  \
    GLOAD(s_ + (long)128 * Kdim, &lds[buf][1][h][4096] + tid * 8);            \
  } while (0)

  // ---- frag-read bases (swizzled)
  const bf16* aBs[2] = {&lds[0][0][0][(wr * 64 + fr) * 64],
                        &lds[1][0][0][(wr * 64 + fr) * 64]};
  const bf16* bBs[2] = {&lds[0][1][0][(wc * 32 + fr) * 64],
                        &lds[1][1][0][(wc * 32 + fr) * 64]};
  const int cofs0 = ((fq + 0) ^ (fr & 7)) * 8;   // kk=0 chunk
  const int cofs1 = ((fq + 4) ^ (fr & 7)) * 8;   // kk=1 chunk

  f32x4 acc[8][4];
#pragma unroll
  for (int m = 0; m < 8; ++m)
#pragma unroll
    for (int n = 0; n < 4; ++n)
      acc[m][n] = (f32x4){0.f, 0.f, 0.f, 0.f};

  bf16x8 aF0[4][2];    // A-half-0 frags (dead after P1; preloaded at P2-end)
  bf16x8 aF1[4][2];    // A-half-1 frags (read at P1)
  bf16x8 bF[2][2][2];  // [nh][n2][kk]; bF0 dead after P2, preloaded P2-end

#define LDA(dst, buf, mh)                                                     \
  { _Pragma("unroll") for (int m4 = 0; m4 < 4; ++m4) {                        \
      dst[m4][0] = *(const bf16x8*)(aBs[buf] + (mh) * 8192 + m4 * 1024 + cofs0); \
      dst[m4][1] = *(const bf16x8*)(aBs[buf] + (mh) * 8192 + m4 * 1024 + cofs1); \
  } }
#define LDB(buf, nh)                                                          \
  { _Pragma("unroll") for (int n2 = 0; n2 < 2; ++n2) {                        \
      bF[nh][n2][0] = *(const bf16x8*)(bBs[buf] + (nh) * 8192 + n2 * 1024 + cofs0); \
      bF[nh][n2][1] = *(const bf16x8*)(bBs[buf] + (nh) * 8192 + n2 * 1024 + cofs1); \
  } }
#define MFMAQ(areg, mh, nh)                                                   \
  { __builtin_amdgcn_s_setprio(1);                                            \
    _Pragma("unroll") for (int m4 = 0; m4 < 4; ++m4)                          \
    _Pragma("unroll") for (int n2 = 0; n2 < 2; ++n2)                          \
    _Pragma("unroll") for (int kk = 0; kk < 2; ++kk)                          \
      acc[(mh) * 4 + m4][(nh) * 2 + n2] =                                     \
          __builtin_amdgcn_mfma_f32_16x16x32_bf16(                            \
              areg[m4][kk], bF[nh][n2][kk], acc[(mh) * 4 + m4][(nh) * 2 + n2],\
              0, 0, 0);                                                       \
    __builtin_amdgcn_s_setprio(0); }

  // Quadrants (0,0)@P0 (0,1)@P1 (1,0)@P2 (1,1)@P3.
  //   P0: MFMA(0,0) [aF0,bF0 preloaded at P2-end(t-1)]; LGKM(4) drains them
  //       (4 left = bF1's reads just issued). Stage A-h1(t+1).
  //   P1: MFMA(0,1) [bF1 phase-old]; LGKM(8) drains bF1's 4. aF1 reads
  //       issued; stage A-h0(t+2). aF0 dead.
  //   P2: MFMA(1,0) [aF1 drained by LGKM(0)]; bF0 dead after this cluster.
  //       VMCNT(6) certifies t+1's {A-h0,B-h0,B-h1}; THEN the 12 cross-tile
  //       preload reads (aF0,bF0 <- t+1) issue -> overlap MFMA(1,1)@P3.
  //       Stage B-h0(t+2).
  //   P3: MFMA(1,1) [aF1,bF1, long drained]. Stage B-h1(t+2); VMCNT(6)
  //       certifies A-h1(t+1) for P1(t+1)'s aF1 reads.
  // WAR: preload reads retire at P0(t+1)'s LGKM(4), >=1 barrier before
  // P1/P2(t+1) restage those slots. In-order DS retire throughout.
#define TILE(bc, bn, t) do {                                                  \
    /* P0 */                                                                  \
    STAGE_A(bn, 1, (t) + 1);                                                  \
    LDB(bc, 1);                                                               \
    BAR; LGKM(4);                                                             \
    MFMAQ(aF0, 0, 0); BAR;                                                    \
    /* P1 */                                                                  \
    STAGE_A(bc, 0, (t) + 2);                                                  \
    LDA(aF1, bc, 1);                                                          \
    BAR; LGKM(8);                                                             \
    MFMAQ(aF0, 0, 1); BAR;                                                    \
    /* P2 */                                                                  \
    STAGE_B(bc, 0, (t) + 2);                                                  \
    BAR; LGKM(0);                                                             \
    MFMAQ(aF1, 1, 0);                                                         \
    VMCNT(6);                                                                 \
    LDA(aF0, bn, 0);                                                          \
    LDB(bn, 0);                                                               \
    BAR;                                                                      \
    /* P3 */                                                                  \
    MFMAQ(aF1, 1, 1);                                                         \
    STAGE_B(bc, 1, (t) + 2);                                                  \
    VMCNT(6); BAR;                                                            \
  } while (0)

  // ---- prologue: tile0 complete + {A-h0,B-h0,B-h1} of tile1, then pre-read
  // tile0's A0/B0 frags (12 reads outstanding into first P0's LGKM(4)).
  STAGE_A(0, 0, 0); STAGE_B(0, 0, 0); STAGE_B(0, 1, 0); STAGE_A(0, 1, 0);
  STAGE_A(1, 0, 1); STAGE_B(1, 0, 1); STAGE_B(1, 1, 1);
  VMCNT(6); BAR;
  LDA(aF0, 0, 0);
  LDB(0, 0);

#pragma unroll 1
  for (int t = 0; t < NT; t += 2) {
    TILE(0, 1, t);        // tail wrap-dummies land only in dead slots /
    TILE(1, 0, t + 1);    // dead registers (audited per-slot)
  }
  VMCNT(0);
  LGKM(0);

  // ---- epilogue: C/D layout col=lane&15, row=(lane>>4)*4+reg
  const int crow = brow + wr * 128 + fq * 4;
  const int ccol = bcol + wc * 64 + fr;
#pragma unroll
  for (int m = 0; m < 8; ++m) {
#pragma unroll
    for (int n = 0; n < 4; ++n) {
      f32x4 v = acc[m][n];
      long base = (long)(crow + m * 16) * Ndim + (ccol + n * 16);
      C[base] = v[0];
      C[base + Ndim] = v[1];
      C[base + 2 * (long)Ndim] = v[2];
      C[base + 3 * (long)Ndim] = v[3];
    }
  }
}

extern "C" void kernel_launch(void* const* d_in, const int* in_sizes, int n_in,
                              void* d_out, int out_size, void* d_ws,
                              size_t ws_size, hipStream_t stream) {
  const float* x = (const float*)d_in[0];       // [4,4096,4096] -> [M,K]
  const float* W = (const float*)d_in[1];       // [N,K]
  const float* lA = (const float*)d_in[2];      // [R,K]
  const float* lB = (const float*)d_in[3];      // [N,R]
  float* out = (float*)d_out;                   // [M,N] f32

  ushort* xb = (ushort*)d_ws;                          // M*K bf16 = 134 MB
  ushort* weff = xb + (size_t)Mdim * Kdim;             // N*K bf16 = 33.5 MB

  cast_x_kernel<<<2048, 256, 0, stream>>>((const float4*)x, (ushort4*)xb,
                                          (Mdim * Kdim) / 4);
  make_weff_kernel<<<(Ndim * (Kdim / 8)) / 256, 256, 0, stream>>>(W, lA, lB,
                                                                  weff);
  dim3 grid((Mdim / BM) * (Ndim / BN));  // 64*16 = 1024 blocks
  gemm256<<<grid, 512, 0, stream>>>((const bf16*)xb, (const bf16*)weff, out);
}

// Round 9
// 560.815 us; speedup vs baseline: 8.5277x; 1.0165x over previous
//
#include <hip/hip_runtime.h>
#include <hip/hip_bf16.h>

// LoRA forward on MI355X:
//   out = x @ W^T + 2.0 * (x @ A^T) @ B^T
// W_eff = W + 2*(B@A) in bf16, xb = bf16(x); one bf16 MFMA GEMM
// C[16384,4096] = xb @ W_eff^T, 256x256, 16x16x32 MFMA, dbuf LDS.
// Round-9: barrier-minimal schedule — 4 phase-end barriers per K-tile
// (mid-phase barriers removed after full WAR/RAW ledger audit), cross-tile
// preload reads moved to P3-start (after the certifying VMCNT+BAR pair).

typedef __bf16 bf16;
typedef bf16 bf16x8 __attribute__((ext_vector_type(8)));
typedef float f32x4 __attribute__((ext_vector_type(4)));

typedef __attribute__((address_space(1))) const void* as1cv;
typedef __attribute__((address_space(3))) void* as3v;

constexpr int Mdim = 16384;
constexpr int Ndim = 4096;
constexpr int Kdim = 4096;
constexpr int Rdim = 8;
constexpr float kScale = 2.0f;  // lora_alpha / r = 16/8

__device__ __forceinline__ unsigned short f2bf(float f) {
  union { float f; unsigned u; } v; v.f = f;
  unsigned u = v.u;
  u += 0x7fffu + ((u >> 16) & 1u);   // round-to-nearest-even
  return (unsigned short)(u >> 16);
}

// ---------------- Kernel 1: cast x (f32) -> xb (bf16) ----------------
__global__ void cast_x_kernel(const float4* __restrict__ x4,
                              ushort4* __restrict__ o4, int n4) {
  int i = blockIdx.x * blockDim.x + threadIdx.x;
  int stride = gridDim.x * blockDim.x;
  for (; i < n4; i += stride) {
    float4 v = x4[i];
    ushort4 o;
    o.x = f2bf(v.x); o.y = f2bf(v.y); o.z = f2bf(v.z); o.w = f2bf(v.w);
    o4[i] = o;
  }
}

// ---------------- Kernel 2: W_eff = W + 2*(B@A), cast to bf16 --------
__global__ void make_weff_kernel(const float* __restrict__ W,
                                 const float* __restrict__ A,
                                 const float* __restrict__ Bm,
                                 ushort* __restrict__ weff) {
  int tid = blockIdx.x * blockDim.x + threadIdx.x;
  int kc = tid & 511;       // K/8 = 512
  int n = tid >> 9;
  if (n >= Ndim) return;

  const float* wp = W + (long)n * Kdim + kc * 8;
  float4 w0 = *(const float4*)(wp);
  float4 w1 = *(const float4*)(wp + 4);

  float4 b0 = *(const float4*)(Bm + n * Rdim);
  float4 b1 = *(const float4*)(Bm + n * Rdim + 4);
  float bs[8] = {b0.x, b0.y, b0.z, b0.w, b1.x, b1.y, b1.z, b1.w};

  float l[8] = {0.f, 0.f, 0.f, 0.f, 0.f, 0.f, 0.f, 0.f};
#pragma unroll
  for (int r = 0; r < Rdim; ++r) {
    const float* ap = A + (long)r * Kdim + kc * 8;
    float4 a0 = *(const float4*)(ap);
    float4 a1 = *(const float4*)(ap + 4);
    l[0] += bs[r] * a0.x; l[1] += bs[r] * a0.y;
    l[2] += bs[r] * a0.z; l[3] += bs[r] * a0.w;
    l[4] += bs[r] * a1.x; l[5] += bs[r] * a1.y;
    l[6] += bs[r] * a1.z; l[7] += bs[r] * a1.w;
  }

  float o[8] = {w0.x + kScale * l[0], w0.y + kScale * l[1],
                w0.z + kScale * l[2], w0.w + kScale * l[3],
                w1.x + kScale * l[4], w1.y + kScale * l[5],
                w1.z + kScale * l[6], w1.w + kScale * l[7]};
  uint4 pk;
  pk.x = (unsigned)f2bf(o[0]) | ((unsigned)f2bf(o[1]) << 16);
  pk.y = (unsigned)f2bf(o[2]) | ((unsigned)f2bf(o[3]) << 16);
  pk.z = (unsigned)f2bf(o[4]) | ((unsigned)f2bf(o[5]) << 16);
  pk.w = (unsigned)f2bf(o[6]) | ((unsigned)f2bf(o[7]) << 16);
  *(uint4*)(weff + (long)n * Kdim + kc * 8) = pk;
}

// ---------------- Kernel 3: C = xb @ W_eff^T, barrier-minimal --------
#define BM 256
#define BN 256
#define BK 64
#define NT (Kdim / BK)   // 64 K-tiles

#define SCHED0 __builtin_amdgcn_sched_barrier(0)
#define BAR __builtin_amdgcn_s_barrier()
#define VMCNT(n) asm volatile("s_waitcnt vmcnt(" #n ")" ::: "memory")
// LGKM keeps a trailing SCHED0: rule #18 (MFMA hoists past inline-asm waits)
#define LGKM(n) do { asm volatile("s_waitcnt lgkmcnt(" #n ")" ::: "memory"); SCHED0; } while (0)
#define GLOAD(src, dst) \
  __builtin_amdgcn_global_load_lds((as1cv)(src), (as3v)(dst), 16, 0, 0)

// Halves by CONSUMPTION quadrant (phase):
//   A half mh: rows { wr*128 + mh*64 + [0,64) : wr=0,1 }
//   B half nh: rows { wc*64 + nh*32 + [0,32) : wc=0..3 }
// Chunk-XOR swizzle: stored 16B chunk cs of row s holds logical chunk cs^(s&7).

__global__ __launch_bounds__(512, 2) void gemm256(const bf16* __restrict__ Xb,
                                                  const bf16* __restrict__ Wb,
                                                  float* __restrict__ C) {
  __shared__ bf16 lds[2][2][2][128 * 64];  // [dbuf][A/B][half][8192] = 128 KiB

  const int tid = threadIdx.x;
  const int lane = tid & 63;
  const int wave = tid >> 6;
  const int wr = wave >> 2;    // 0..1  (M half)
  const int wc = wave & 3;     // 0..3  (N quarter)
  const int fr = lane & 15;
  const int fq = lane >> 4;

  // XCD-aware bijective swizzle: 1024 blocks, 8 XCDs, 128 contiguous per XCD
  const int wg = blockIdx.x;
  const int swz = (wg & 7) * 128 + (wg >> 3);
  const int by = swz >> 4;     // 0..63  (M block)
  const int bx = swz & 15;     // 0..15  (N block)
  const int brow = by * BM;
  const int bcol = bx * BN;

  // ---- staging pointers (per thread): storage row sLow, swizzled chunk
  const int sLow = tid >> 3;                       // 0..63
  const int cg = (tid & 7) ^ (sLow & 7);           // logical chunk (involution)
  const bf16* pA = Xb + (long)(brow + sLow) * Kdim + cg * 8;
  const bf16* pB =
      Wb + (long)(bcol + (sLow & 31) + (sLow >> 5) * 64) * Kdim + cg * 8;

#define STAGE_A(buf, h, kt) do {                                              \
    const bf16* s_ = pA + (long)((h) * 64) * Kdim + (((kt) & (NT - 1)) * 64); \
    GLOAD(s_, &lds[buf][0][h][0] + tid * 8);                                  \
    GLOAD(s_ + (long)128 * Kdim, &lds[buf][0][h][4096] + tid * 8);            \
  } while (0)
#define STAGE_B(buf, h, kt) do {                                              \
    const bf16* s_ = pB + (long)((h) * 32) * Kdim + (((kt) & (NT - 1)) * 64); \
    GLOAD(s_, &lds[buf][1][h][0] + tid * 8);                                  \
    GLOAD(s_ + (long)128 * Kdim, &lds[buf][1][h][4096] + tid * 8);            \
  } while (0)

  // ---- frag-read bases (swizzled)
  const bf16* aBs[2] = {&lds[0][0][0][(wr * 64 + fr) * 64],
                        &lds[1][0][0][(wr * 64 + fr) * 64]};
  const bf16* bBs[2] = {&lds[0][1][0][(wc * 32 + fr) * 64],
                        &lds[1][1][0][(wc * 32 + fr) * 64]};
  const int cofs0 = ((fq + 0) ^ (fr & 7)) * 8;   // kk=0 chunk
  const int cofs1 = ((fq + 4) ^ (fr & 7)) * 8;   // kk=1 chunk

  f32x4 acc[8][4];
#pragma unroll
  for (int m = 0; m < 8; ++m)
#pragma unroll
    for (int n = 0; n < 4; ++n)
      acc[m][n] = (f32x4){0.f, 0.f, 0.f, 0.f};

  bf16x8 aF0[4][2];    // A-half-0 frags (dead after P1; cross-preloaded @P3)
  bf16x8 aF1[4][2];    // A-half-1 frags (read at P1)
  bf16x8 bF[2][2][2];  // [nh][n2][kk]; bF0 cross-preloaded @P3

#define LDA(dst, buf, mh)                                                     \
  { _Pragma("unroll") for (int m4 = 0; m4 < 4; ++m4) {                        \
      dst[m4][0] = *(const bf16x8*)(aBs[buf] + (mh) * 8192 + m4 * 1024 + cofs0); \
      dst[m4][1] = *(const bf16x8*)(aBs[buf] + (mh) * 8192 + m4 * 1024 + cofs1); \
  } }
#define LDB(buf, nh)                                                          \
  { _Pragma("unroll") for (int n2 = 0; n2 < 2; ++n2) {                        \
      bF[nh][n2][0] = *(const bf16x8*)(bBs[buf] + (nh) * 8192 + n2 * 1024 + cofs0); \
      bF[nh][n2][1] = *(const bf16x8*)(bBs[buf] + (nh) * 8192 + n2 * 1024 + cofs1); \
  } }
#define MFMAQ(areg, mh, nh)                                                   \
  { __builtin_amdgcn_s_setprio(1);                                            \
    _Pragma("unroll") for (int m4 = 0; m4 < 4; ++m4)                          \
    _Pragma("unroll") for (int n2 = 0; n2 < 2; ++n2)                          \
    _Pragma("unroll") for (int kk = 0; kk < 2; ++kk)                          \
      acc[(mh) * 4 + m4][(nh) * 2 + n2] =                                     \
          __builtin_amdgcn_mfma_f32_16x16x32_bf16(                            \
              areg[m4][kk], bF[nh][n2][kk], acc[(mh) * 4 + m4][(nh) * 2 + n2],\
              0, 0, 0);                                                       \
    __builtin_amdgcn_s_setprio(0); }

  // Quadrants (0,0)@P0 (0,1)@P1 (1,0)@P2 (1,1)@P3; ONE barrier per phase.
  // DS ledger (in-order retire):
  //   P0: LGKM(4) drains P3's 12 cross reads (leaves LDB1's 4).
  //   P1: LGKM(8) drains LDB1's 4 (leaves aF1's 8).
  //   P2: LGKM(0) drains aF1's 8.
  //   P3: 12 cross reads (aF0,bF0 <- t+1) issued post-BAR (certified by
  //       VMCNT(6)@P2 + BAR); they drain at P0(t+1)'s LGKM(4).
  // VM ledger: VMCNT(6)@P2 retires t+1's {A-h0,B-h0,B-h1} (staged P1,P2,P3
  //   of t-1); VMCNT(6)@P3 retires A-h1(t+1) (staged P0(t)).
  // WAR: every restage has >=1 phase-end barrier after its readers' drain:
  //   A-h1(bn)@P0 <- aF1 drained LGKM(0)@P2(t-1), BARs P2,P3(t-1).
  //   A-h0(bc)@P1 <- cross-read drained LGKM(4)@P0(t), BAR P0.
  //   B-h0(bc)@P2 <- cross-read drained LGKM(4)@P0(t), BARs P0,P1.
  //   B-h1(bc)@P3 <- LDB1 drained LGKM(8)@P1(t), BARs P1,P2.
#define TILE(bc, bn, t) do {                                                  \
    /* P0 */                                                                  \
    STAGE_A(bn, 1, (t) + 1);                                                  \
    LDB(bc, 1);                                                               \
    LGKM(4);                                                                  \
    MFMAQ(aF0, 0, 0);                                                         \
    BAR;                                                                      \
    /* P1 */                                                                  \
    STAGE_A(bc, 0, (t) + 2);                                                  \
    LDA(aF1, bc, 1);                                                          \
    LGKM(8);                                                                  \
    MFMAQ(aF0, 0, 1);                                                         \
    BAR;                                                                      \
    /* P2 */                                                                  \
    STAGE_B(bc, 0, (t) + 2);                                                  \
    LGKM(0);                                                                  \
    MFMAQ(aF1, 1, 0);                                                         \
    VMCNT(6);                                                                 \
    BAR;                                                                      \
    /* P3 */                                                                  \
    LDA(aF0, bn, 0);                                                          \
    LDB(bn, 0);                                                               \
    MFMAQ(aF1, 1, 1);                                                         \
    STAGE_B(bc, 1, (t) + 2);                                                  \
    VMCNT(6);                                                                 \
    BAR;                                                                      \
  } while (0)

  // ---- prologue: tile0 complete + {A-h0,B-h0,B-h1} of tile1, then pre-read
  // tile0's A0/B0 frags (12 reads outstanding into first P0's LGKM(4)).
  STAGE_A(0, 0, 0); STAGE_B(0, 0, 0); STAGE_B(0, 1, 0); STAGE_A(0, 1, 0);
  STAGE_A(1, 0, 1); STAGE_B(1, 0, 1); STAGE_B(1, 1, 1);
  VMCNT(6); BAR;
  LDA(aF0, 0, 0);
  LDB(0, 0);

#pragma unroll 1
  for (int t = 0; t < NT; t += 2) {
    TILE(0, 1, t);        // tail wrap-dummies land only in dead slots /
    TILE(1, 0, t + 1);    // dead registers (audited per-slot)
  }
  VMCNT(0);
  LGKM(0);

  // ---- epilogue: C/D layout col=lane&15, row=(lane>>4)*4+reg
  const int crow = brow + wr * 128 + fq * 4;
  const int ccol = bcol + wc * 64 + fr;
#pragma unroll
  for (int m = 0; m < 8; ++m) {
#pragma unroll
    for (int n = 0; n < 4; ++n) {
      f32x4 v = acc[m][n];
      long base = (long)(crow + m * 16) * Ndim + (ccol + n * 16);
      C[base] = v[0];
      C[base + Ndim] = v[1];
      C[base + 2 * (long)Ndim] = v[2];
      C[base + 3 * (long)Ndim] = v[3];
    }
  }
}

extern "C" void kernel_launch(void* const* d_in, const int* in_sizes, int n_in,
                              void* d_out, int out_size, void* d_ws,
                              size_t ws_size, hipStream_t stream) {
  const float* x = (const float*)d_in[0];       // [4,4096,4096] -> [M,K]
  const float* W = (const float*)d_in[1];       // [N,K]
  const float* lA = (const float*)d_in[2];      // [R,K]
  const float* lB = (const float*)d_in[3];      // [N,R]
  float* out = (float*)d_out;                   // [M,N] f32

  ushort* xb = (ushort*)d_ws;                          // M*K bf16 = 134 MB
  ushort* weff = xb + (size_t)Mdim * Kdim;             // N*K bf16 = 33.5 MB

  cast_x_kernel<<<2048, 256, 0, stream>>>((const float4*)x, (ushort4*)xb,
                                          (Mdim * Kdim) / 4);
  make_weff_kernel<<<(Ndim * (Kdim / 8)) / 256, 256, 0, stream>>>(W, lA, lB,
                                                                  weff);
  dim3 grid((Mdim / BM) * (Ndim / BN));  // 64*16 = 1024 blocks
  gemm256<<<grid, 512, 0, stream>>>((const bf16*)xb, (const bf16*)weff, out);
}